// Round 6
// baseline (176.923 us; speedup 1.0000x reference)
//
#include <hip/hip_runtime.h>

#define F_IN 128
#define F_OUT 64
#define GROWS 128        // rows per gemm block
#define XBSTRIDE 136     // bf16 elems per LDS row (272 B = 17x16B, aligned+padded)

#define NPB 128          // nodes per bucket (r1-proven best)
#define NPB_SHIFT 7
#define BCAP 800         // max buckets (nb = 782)
#define ECAP 2240        // edges staged per LDS chunk in baccum (r1-proven)
#define TILE 8192        // edges per tile in multisplit
#define BSTH 1024        // fused-kernel threads
#define TMAX 256         // max tiles (T = ceil(E/TILE) = 196)

// fp32 -> bf16 round-to-nearest-even.
__device__ inline unsigned f2bf(float f) {
    const unsigned u = __float_as_uint(f);
    return (u + 0x7FFFu + ((u >> 16) & 1u)) >> 16;
}
__device__ inline float bf_lo(unsigned u) { return __uint_as_float(u << 16); }
__device__ inline float bf_hi(unsigned u) { return __uint_as_float(u & 0xFFFF0000u); }

// MFMA fragment types (guide §3: 8 bf16 = 4 VGPRs, 4 fp32 acc).
using bf16x8 = __attribute__((ext_vector_type(8))) short;
using f32x4  = __attribute__((ext_vector_type(4))) float;

// Shared-memory union: gemm role vs multisplit role (whole-block roles).
struct GemmSh {
    unsigned short xt[GROWS * XBSTRIDE];    // 34.8 KB bf16 x tile (k contiguous per row)
    unsigned short wth[F_OUT * XBSTRIDE];   // 17.4 KB w^T hi  (bf16, [col][k])
    unsigned short wtl[F_OUT * XBSTRIDE];   // 17.4 KB w^T lo residual (bf16, [col][k])
};                                          // = 69.6 KB
struct ScatSh {
    int2 ebuf2[TILE];                        // 64 KB (rank-permuted records)
    int  h[BCAP];                            // 3.2 KB
    int  lcur[BCAP];                         // 3.2 KB
    int  wsum[16];
    int  woff[16];
};                                           // = 70.6 KB
union FusedSh { GemmSh g; ScatSh s; };       // ~70.6 KB -> 2 blocks/CU

// ---------------------------------------------------------------------------
// Fused kernel: blocks [0,T) = tile-private edge multisplit; blocks [T,T+G) =
// support = x @ w via MFMA 16x16x32 bf16 (w split hi+lo bf16 ~= fp32 weights).
// toff written TRANSPOSED: toff[bucket*T + tile] (coalesced baccum prologue).
// ---------------------------------------------------------------------------
__global__ __launch_bounds__(BSTH) void fused_kernel(const float* __restrict__ x,
                                                     const float* __restrict__ w,
                                                     unsigned short* __restrict__ support,
                                                     int n_nodes,
                                                     const float* __restrict__ edge_val,
                                                     const int* __restrict__ edge_src,
                                                     const int* __restrict__ edge_dst,
                                                     int* __restrict__ toff,
                                                     int2* __restrict__ sorted,
                                                     int n_edges, int nb, int T) {
    __shared__ FusedSh u;
    const int tid = threadIdx.x;

    if ((int)blockIdx.x >= T) {
        // ================= gemm role (MFMA) =================
        const int row0 = (blockIdx.x - T) * GROWS;

        {   // stage w^T as bf16 hi/lo: thread i -> col = i&63, k = (i>>6)*8 .. +7
            #pragma unroll
            for (int i = tid; i < F_OUT * (F_IN / 8); i += BSTH) {   // 1024 items
                const int col = i & 63;
                const int kb  = (i >> 6) << 3;
                unsigned short sh[8], sl[8];
                #pragma unroll
                for (int j = 0; j < 8; ++j) {
                    const float f = w[(size_t)(kb + j) * F_OUT + col];   // coalesced per j
                    const unsigned h = f2bf(f);
                    sh[j] = (unsigned short)h;
                    sl[j] = (unsigned short)f2bf(f - __uint_as_float(h << 16));
                }
                uint4 oh, ol;
                oh.x = sh[0] | ((unsigned)sh[1] << 16); oh.y = sh[2] | ((unsigned)sh[3] << 16);
                oh.z = sh[4] | ((unsigned)sh[5] << 16); oh.w = sh[6] | ((unsigned)sh[7] << 16);
                ol.x = sl[0] | ((unsigned)sl[1] << 16); ol.y = sl[2] | ((unsigned)sl[3] << 16);
                ol.z = sl[4] | ((unsigned)sl[5] << 16); ol.w = sl[6] | ((unsigned)sl[7] << 16);
                *(uint4*)&u.g.wth[col * XBSTRIDE + kb] = oh;
                *(uint4*)&u.g.wtl[col * XBSTRIDE + kb] = ol;
            }
        }
        {   // stage x tile as bf16: 128 rows x 16 chunks of 8 k's, 2/thread
            const float4* x4 = (const float4*)x;
            #pragma unroll
            for (int i = tid; i < GROWS * (F_IN / 8); i += BSTH) {
                const int r  = i >> 4;       // row 0..127
                const int k8 = i & 15;       // 8-k chunk 0..15
                const int row = row0 + r;
                float4 a = make_float4(0.f, 0.f, 0.f, 0.f);
                float4 b = make_float4(0.f, 0.f, 0.f, 0.f);
                if (row < n_nodes) {
                    a = x4[(size_t)row * (F_IN / 4) + 2 * k8 + 0];
                    b = x4[(size_t)row * (F_IN / 4) + 2 * k8 + 1];
                }
                uint4 o;
                o.x = f2bf(a.x) | (f2bf(a.y) << 16);
                o.y = f2bf(a.z) | (f2bf(a.w) << 16);
                o.z = f2bf(b.x) | (f2bf(b.y) << 16);
                o.w = f2bf(b.z) | (f2bf(b.w) << 16);
                *(uint4*)&u.g.xt[r * XBSTRIDE + k8 * 8] = o;   // 16B aligned
            }
        }
        __syncthreads();

        const int ln = tid & 63;
        const int wv = tid >> 6;             // wave 0..15
        const int rt = wv >> 1;              // row-tile 0..7
        const int cp = (wv & 1) << 1;        // col-tile base: 0 or 2
        const int lr = ln >> 4;              // 0..3 (k-subchunk / out row-quad)
        const int lc = ln & 15;

        const unsigned short* ar  = &u.g.xt [(rt * 16 + lc) * XBSTRIDE + lr * 8];
        const unsigned short* bh0 = &u.g.wth[(cp * 16 + lc) * XBSTRIDE + lr * 8];
        const unsigned short* bh1 = &u.g.wth[((cp + 1) * 16 + lc) * XBSTRIDE + lr * 8];
        const unsigned short* bl0 = &u.g.wtl[(cp * 16 + lc) * XBSTRIDE + lr * 8];
        const unsigned short* bl1 = &u.g.wtl[((cp + 1) * 16 + lc) * XBSTRIDE + lr * 8];

        f32x4 acc0 = {0.f, 0.f, 0.f, 0.f};
        f32x4 acc1 = {0.f, 0.f, 0.f, 0.f};
        #pragma unroll
        for (int kc = 0; kc < 4; ++kc) {
            const bf16x8 a  = *(const bf16x8*)(ar  + kc * 32);
            const bf16x8 h0 = *(const bf16x8*)(bh0 + kc * 32);
            const bf16x8 h1 = *(const bf16x8*)(bh1 + kc * 32);
            const bf16x8 l0 = *(const bf16x8*)(bl0 + kc * 32);
            const bf16x8 l1 = *(const bf16x8*)(bl1 + kc * 32);
            acc0 = __builtin_amdgcn_mfma_f32_16x16x32_bf16(a, h0, acc0, 0, 0, 0);
            acc1 = __builtin_amdgcn_mfma_f32_16x16x32_bf16(a, h1, acc1, 0, 0, 0);
            acc0 = __builtin_amdgcn_mfma_f32_16x16x32_bf16(a, l0, acc0, 0, 0, 0);
            acc1 = __builtin_amdgcn_mfma_f32_16x16x32_bf16(a, l1, acc1, 0, 0, 0);
        }

        #pragma unroll
        for (int i = 0; i < 4; ++i) {
            const int row = row0 + rt * 16 + lr * 4 + i;
            if (row < n_nodes) {
                unsigned short* sp = &support[(size_t)row * F_OUT + lc];
                sp[cp * 16]       = (unsigned short)f2bf(acc0[i]);
                sp[(cp + 1) * 16] = (unsigned short)f2bf(acc1[i]);
            }
        }
        return;
    }

    // ================= multisplit role =================
    const int te  = blockIdx.x * TILE;
    const int cnt = min(TILE, n_edges - te);

    for (int i = tid; i < BCAP; i += BSTH) u.s.h[i] = 0;
    __syncthreads();

    // Pass A: load edges into REGISTERS (2 int4-tiles/thread) + LDS hist.
    const int cnt4 = cnt >> 2;
    const int4*   s4 = (const int4*)(edge_src + te);
    const int4*   d4 = (const int4*)(edge_dst + te);
    const float4* v4 = (const float4*)(edge_val + te);
    int4 rs[2], rd[2]; float4 rv[2];
    #pragma unroll
    for (int it = 0; it < 2; ++it) {
        const int t = tid + it * BSTH;
        if (t < cnt4) {
            rs[it] = s4[t]; rd[it] = d4[t]; rv[it] = v4[t];
            atomicAdd(&u.s.h[rd[it].x >> NPB_SHIFT], 1);
            atomicAdd(&u.s.h[rd[it].y >> NPB_SHIFT], 1);
            atomicAdd(&u.s.h[rd[it].z >> NPB_SHIFT], 1);
            atomicAdd(&u.s.h[rd[it].w >> NPB_SHIFT], 1);
        }
    }
    if (tid == 0) {   // tail (<=3 edges): hist only, ranked in pass B
        for (int e = cnt4 << 2; e < cnt; ++e)
            atomicAdd(&u.s.h[edge_dst[te + e] >> NPB_SHIFT], 1);
    }
    __syncthreads();

    // Shuffle-based block scan of bucket counts (16 waves).
    const int v = (tid < nb) ? u.s.h[tid] : 0;
    int s = v;
    #pragma unroll
    for (int off = 1; off < 64; off <<= 1) {
        const int t = __shfl_up(s, off, 64);
        if ((tid & 63) >= off) s += t;
    }
    const int wave = tid >> 6;
    if ((tid & 63) == 63) u.s.wsum[wave] = s;
    __syncthreads();
    if (tid < 16) {
        const int ws = u.s.wsum[tid];
        int sc = ws;
        #pragma unroll
        for (int off = 1; off < 16; off <<= 1) {
            const int t = __shfl_up(sc, off, 64);
            if (tid >= off) sc += t;
        }
        u.s.woff[tid] = sc - ws;   // exclusive wave offset
    }
    __syncthreads();

    {   // TRANSPOSED toff stores: toff[bucket*T + tile]
        const int bid = blockIdx.x;
        if (tid < nb) {
            const int start = s + u.s.woff[wave] - v;   // exclusive start
            u.s.lcur[tid] = start;
            toff[(size_t)tid * T + bid] = start;
        }
        if (tid == 0) toff[(size_t)nb * T + bid] = cnt;
    }
    __syncthreads();

    // Pass B: rank (LDS cursor) and write records DIRECTLY permuted into LDS.
    #pragma unroll
    for (int it = 0; it < 2; ++it) {
        const int t = tid + it * BSTH;
        if (t < cnt4) {
            int b, r;
            b = rd[it].x >> NPB_SHIFT; r = atomicAdd(&u.s.lcur[b], 1);
            u.s.ebuf2[r] = make_int2(rs[it].x | ((rd[it].x & (NPB - 1)) << 20), __float_as_int(rv[it].x));
            b = rd[it].y >> NPB_SHIFT; r = atomicAdd(&u.s.lcur[b], 1);
            u.s.ebuf2[r] = make_int2(rs[it].y | ((rd[it].y & (NPB - 1)) << 20), __float_as_int(rv[it].y));
            b = rd[it].z >> NPB_SHIFT; r = atomicAdd(&u.s.lcur[b], 1);
            u.s.ebuf2[r] = make_int2(rs[it].z | ((rd[it].z & (NPB - 1)) << 20), __float_as_int(rv[it].z));
            b = rd[it].w >> NPB_SHIFT; r = atomicAdd(&u.s.lcur[b], 1);
            u.s.ebuf2[r] = make_int2(rs[it].w | ((rd[it].w & (NPB - 1)) << 20), __float_as_int(rv[it].w));
        }
    }
    if (tid == 0) {   // tail
        for (int e = cnt4 << 2; e < cnt; ++e) {
            const int dd = edge_dst[te + e];
            const int b = dd >> NPB_SHIFT;
            const int r = atomicAdd(&u.s.lcur[b], 1);
            u.s.ebuf2[r] = make_int2(edge_src[te + e] | ((dd & (NPB - 1)) << 20),
                                     __float_as_int(edge_val[te + e]));
        }
    }
    __syncthreads();

    // Pass C: stream the sorted tile to its private region (coalesced).
    for (int k = tid; k < cnt; k += BSTH)
        sorted[(size_t)te + k] = u.s.ebuf2[k];
}

// ---------------------------------------------------------------------------
// baccum v3: segment-copy staging (fast path) + chunked-binsearch fallback.
// Fast path (total <= ECAP, the overwhelmingly common case): the per-record
// 8-step dependent binary search (~1000 cy of serial ds_read latency per
// record) is replaced by direct cooperative copies of the 196 tile segments
// (wave w owns tiles w, w+8, ...; all loads independent).  Staging goes
// DIRECTLY into node-grouped ebuf2 via a 2-pass read (pass 1: hist only;
// pass 2: L2-hot re-read + cursor placement) -> the ebuf write/read/permute
// and one barrier are deleted.  Slow path = r1-proven chunked code (any
// distribution stays correct).  Plain __launch_bounds__(512): r2 proved a
// min-waves clause forces spill.  LDS fp atomics are poison (r4: CAS loop).
// ---------------------------------------------------------------------------
__global__ __launch_bounds__(512) void baccum_kernel(const unsigned short* __restrict__ support,
                                                     const int2* __restrict__ sorted,
                                                     const int* __restrict__ toff,
                                                     float* __restrict__ out,
                                                     int n_nodes, int T, int nb) {
    __shared__ int2 ebuf[ECAP];      // slow path only
    __shared__ int2 ebuf2[ECAP];
    __shared__ int tstart[TMAX];
    __shared__ int toffb[TMAX];
    __shared__ int tlen_s[TMAX];
    __shared__ int wsum3[4];
    __shared__ int total_s;
    __shared__ int hist[NPB];
    __shared__ int node_off[NPB + 1];
    __shared__ int cursor[NPB];
    __shared__ int wsum2[2];

    const int tid = threadIdx.x;
    const int b = blockIdx.x;

    int mycnt = 0, myoff = 0;
    if (tid < TMAX) {
        if (tid < T) {
            const int s0 = toff[(size_t)b * T + tid];          // coalesced row b
            const int e0 = toff[(size_t)(b + 1) * T + tid];    // coalesced row b+1
            toffb[tid] = s0;
            mycnt = e0 - s0;
            tlen_s[tid] = mycnt;
        }
        int s = mycnt;
        #pragma unroll
        for (int off = 1; off < 64; off <<= 1) {
            const int t = __shfl_up(s, off, 64);
            if ((tid & 63) >= off) s += t;
        }
        if ((tid & 63) == 63) wsum3[tid >> 6] = s;
        myoff = s - mycnt;
    }
    __syncthreads();
    if (tid < TMAX && tid < T) {
        int add = 0;
        const int wv = tid >> 6;
        for (int q2 = 0; q2 < wv; ++q2) add += wsum3[q2];
        tstart[tid] = myoff + add;
    }
    if (tid == 0) total_s = wsum3[0] + wsum3[1] + wsum3[2] + wsum3[3];
    __syncthreads();
    const int total = total_s;

    const int g8 = tid >> 3;        // group 0..63 (owns nodes g8, g8+64)
    const int q  = tid & 7;         // uint4 slot: feats 8q..8q+7
    const uint4* sup = (const uint4*)support;   // row = 8 uint4 = 128 B

    float4 accA[2], accB[2];        // node j: feats 8q..8q+3 / 8q+4..8q+7
    #pragma unroll
    for (int j = 0; j < 2; ++j) {
        accA[j] = make_float4(0.f, 0.f, 0.f, 0.f);
        accB[j] = make_float4(0.f, 0.f, 0.f, 0.f);
    }

    // Shared phase bodies.
    auto scan_bins = [&]() {   // hist -> node_off (+1-incl), cursor (excl)
        int v = 0;
        if (tid < NPB) v = hist[tid];
        int s = v;
        if (tid < NPB) {
            #pragma unroll
            for (int off = 1; off < 64; off <<= 1) {
                const int t = __shfl_up(s, off, 64);
                if ((tid & 63) >= off) s += t;
            }
            if ((tid & 63) == 63) wsum2[tid >> 6] = s;
        }
        __syncthreads();
        if (tid < NPB) {
            const int incl = s + ((tid >= 64) ? wsum2[0] : 0);
            node_off[tid + 1] = incl;
            cursor[tid] = incl - v;
            if (tid == 0) node_off[0] = 0;
        }
    };
    auto gather = [&]() {      // ebuf2[node_off[nl]..] -> register acc
        #pragma unroll
        for (int j = 0; j < 2; ++j) {
            const int nl = g8 + 64 * j;
            int k = node_off[nl];
            const int ke = node_off[nl + 1];
            float4 aA = accA[j], aB = accB[j];
            while (k + 8 <= ke) {
                int2 e[8];
                uint4 s8[8];
                #pragma unroll
                for (int u2 = 0; u2 < 8; ++u2) e[u2] = ebuf2[k + u2];      // broadcast
                #pragma unroll
                for (int u2 = 0; u2 < 8; ++u2)
                    s8[u2] = sup[(size_t)(e[u2].x & 0xFFFFF) * 8 + q];     // independent
                #pragma unroll
                for (int u2 = 0; u2 < 8; ++u2) {
                    const float v = __int_as_float(e[u2].y);
                    aA.x += v * bf_lo(s8[u2].x); aA.y += v * bf_hi(s8[u2].x);
                    aA.z += v * bf_lo(s8[u2].y); aA.w += v * bf_hi(s8[u2].y);
                    aB.x += v * bf_lo(s8[u2].z); aB.y += v * bf_hi(s8[u2].z);
                    aB.z += v * bf_lo(s8[u2].w); aB.w += v * bf_hi(s8[u2].w);
                }
                k += 8;
            }
            for (; k < ke; ++k) {
                const int2 e0 = ebuf2[k];
                const uint4 s0 = sup[(size_t)(e0.x & 0xFFFFF) * 8 + q];
                const float v0 = __int_as_float(e0.y);
                aA.x += v0 * bf_lo(s0.x); aA.y += v0 * bf_hi(s0.x);
                aA.z += v0 * bf_lo(s0.y); aA.w += v0 * bf_hi(s0.y);
                aB.x += v0 * bf_lo(s0.z); aB.y += v0 * bf_hi(s0.z);
                aB.z += v0 * bf_lo(s0.w); aB.w += v0 * bf_hi(s0.w);
            }
            accA[j] = aA; accB[j] = aB;
        }
    };

    if (total <= ECAP) {
        // ======== fast path: single chunk, segment-copy, no binsearch ========
        if (tid < NPB) hist[tid] = 0;
        __syncthreads();

        const int wv = tid >> 6;
        const int ln = tid & 63;

        // Pass 1: histogram (per-tile cooperative reads; all loads independent).
        for (int t = wv; t < T; t += 8) {
            const int len = tlen_s[t];
            const size_t gbase = (size_t)t * TILE + toffb[t];
            for (int j = ln; j < len; j += 64) {
                const int2 ev = sorted[gbase + j];
                atomicAdd(&hist[((unsigned)ev.x) >> 20], 1);
            }
        }
        __syncthreads();

        scan_bins();
        __syncthreads();

        // Pass 2: re-read (L2-hot) and place directly into node-grouped ebuf2.
        for (int t = wv; t < T; t += 8) {
            const int len = tlen_s[t];
            const size_t gbase = (size_t)t * TILE + toffb[t];
            for (int j = ln; j < len; j += 64) {
                const int2 ev = sorted[gbase + j];
                const int r = atomicAdd(&cursor[((unsigned)ev.x) >> 20], 1);
                ebuf2[r] = ev;
            }
        }
        __syncthreads();

        gather();
    } else {
        // ======== slow path: r1-proven chunked binsearch (any distribution) ====
        for (int cb = 0; cb < total; cb += ECAP) {
            const int cnt = min(ECAP, total - cb);

            __syncthreads();
            if (tid < NPB) hist[tid] = 0;
            __syncthreads();

            for (int i = tid; i < cnt; i += 512) {
                const int g = cb + i;
                int lo = 0, hi = T - 1;
                while (lo < hi) {
                    const int mid = (lo + hi + 1) >> 1;
                    if (tstart[mid] <= g) lo = mid; else hi = mid - 1;
                }
                const int2 ev = sorted[(size_t)lo * TILE + toffb[lo] + (g - tstart[lo])];
                ebuf[i] = ev;
                atomicAdd(&hist[((unsigned)ev.x) >> 20], 1);
            }
            __syncthreads();

            scan_bins();
            __syncthreads();

            for (int i = tid; i < cnt; i += 512) {
                const int2 ev = ebuf[i];
                const int r = atomicAdd(&cursor[((unsigned)ev.x) >> 20], 1);
                ebuf2[r] = ev;
            }
            __syncthreads();

            gather();
        }
    }

    // Writeout (empty buckets write zeros; ReLU(0)=0 matches segment_sum).
    const int base = b << NPB_SHIFT;
    #pragma unroll
    for (int j = 0; j < 2; ++j) {
        const int node = base + g8 + 64 * j;
        if (node < n_nodes) {
            float4 vA = accA[j], vB = accB[j];
            vA.x = fmaxf(vA.x, 0.f); vA.y = fmaxf(vA.y, 0.f);
            vA.z = fmaxf(vA.z, 0.f); vA.w = fmaxf(vA.w, 0.f);
            vB.x = fmaxf(vB.x, 0.f); vB.y = fmaxf(vB.y, 0.f);
            vB.z = fmaxf(vB.z, 0.f); vB.w = fmaxf(vB.w, 0.f);
            ((float4*)out)[(size_t)node * 16 + 2 * q + 0] = vA;
            ((float4*)out)[(size_t)node * 16 + 2 * q + 1] = vB;
        }
    }
}

// ---------------------------------------------------------------------------
// Fallback: atomic path with bf16 support.
// ---------------------------------------------------------------------------
__global__ __launch_bounds__(256) void scatter_kernel(const unsigned short* __restrict__ support,
                                                      const float* __restrict__ edge_val,
                                                      const int* __restrict__ edge_src,
                                                      const int* __restrict__ edge_dst,
                                                      float* __restrict__ out,
                                                      int n_edges) {
    const long gid = (long)blockIdx.x * blockDim.x + threadIdx.x;
    const int e = (int)(gid >> 4);
    if (e >= n_edges) return;
    const int q = (int)(gid & 15);
    const int src   = edge_src[e];
    const int dst   = edge_dst[e];
    const float val = edge_val[e];
    const uint2 s = ((const uint2*)support)[(size_t)src * 16 + q];
    float* o = &out[(size_t)dst * F_OUT + q * 4];
    atomicAdd(o + 0, val * bf_lo(s.x));
    atomicAdd(o + 1, val * bf_hi(s.x));
    atomicAdd(o + 2, val * bf_lo(s.y));
    atomicAdd(o + 3, val * bf_hi(s.y));
}

__global__ __launch_bounds__(256) void relu_kernel(float* __restrict__ out, int n4) {
    const int i = blockIdx.x * blockDim.x + threadIdx.x;
    if (i < n4) {
        float4 v = ((float4*)out)[i];
        v.x = fmaxf(v.x, 0.f); v.y = fmaxf(v.y, 0.f);
        v.z = fmaxf(v.z, 0.f); v.w = fmaxf(v.w, 0.f);
        ((float4*)out)[i] = v;
    }
}

extern "C" void kernel_launch(void* const* d_in, const int* in_sizes, int n_in,
                              void* d_out, int out_size, void* d_ws, size_t ws_size,
                              hipStream_t stream) {
    const float* x        = (const float*)d_in[0];
    const float* w        = (const float*)d_in[1];
    const float* edge_val = (const float*)d_in[2];
    const int*   edge_src = (const int*)d_in[3];
    const int*   edge_dst = (const int*)d_in[4];
    float* out = (float*)d_out;

    const int n_nodes = in_sizes[0] / F_IN;   // 100000
    const int n_edges = in_sizes[2];          // 1600000
    const int nb = (n_nodes + NPB - 1) >> NPB_SHIFT;   // 782 buckets
    const int T  = (n_edges + TILE - 1) / TILE;        // 196 tiles
    const int G  = (n_nodes + GROWS - 1) / GROWS;      // 782 gemm blocks

    // Workspace: support bf16 (12.8 MB) | sorted (12.85 MB) | toff (0.61 MB)
    char* p = (char*)d_ws;
    unsigned short* support = (unsigned short*)p;
    p += (size_t)n_nodes * F_OUT * sizeof(unsigned short);
    p = (char*)(((size_t)p + 15) & ~(size_t)15);
    int2* sorted = (int2*)p;  p += (size_t)T * TILE * sizeof(int2);
    int*  toff   = (int*)p;   p += (size_t)(nb + 1) * T * sizeof(int);
    const size_t ws_needed = (size_t)(p - (char*)d_ws);

    const bool ok = (ws_size >= ws_needed) && (nb <= BCAP) && (n_nodes < (1 << 20))
                    && (T <= TMAX);
    if (ok) {
        fused_kernel<<<T + G, BSTH, 0, stream>>>(x, w, support, n_nodes,
                                                 edge_val, edge_src, edge_dst,
                                                 toff, sorted, n_edges, nb, T);
        baccum_kernel<<<nb, 512, 0, stream>>>(support, sorted, toff, out,
                                              n_nodes, T, nb);
    } else {
        // gemm only (T=0 -> all blocks take the gemm role)
        fused_kernel<<<G, BSTH, 0, stream>>>(x, w, support, n_nodes,
                                             edge_val, edge_src, edge_dst,
                                             nullptr, nullptr, n_edges, nb, 0);
        hipMemsetAsync(d_out, 0, (size_t)out_size * sizeof(float), stream);
        const long st = (long)n_edges * 16;
        scatter_kernel<<<(int)((st + 255) / 256), 256, 0, stream>>>(
            support, edge_val, edge_src, edge_dst, out, n_edges);
        const int n4o = out_size / 4;
        relu_kernel<<<(n4o + 255) / 256, 256, 0, stream>>>(out, n4o);
    }
}

// Round 7
// 153.290 us; speedup vs baseline: 1.1542x; 1.1542x over previous
//
#include <hip/hip_runtime.h>

#define F_IN 128
#define F_OUT 64
#define GROWS 128        // rows per gemm block
#define XBSTRIDE 136     // bf16 elems per LDS row (272 B = 17x16B, aligned+padded)

#define NPB 128          // nodes per bucket (r1-proven best)
#define NPB_SHIFT 7
#define BCAP 800         // max buckets (nb = 782)
#define ECAP 2240        // edges staged per LDS chunk in baccum (r1-proven)
#define TILE 8192        // edges per tile in multisplit
#define BSTH 1024        // fused-kernel threads
#define TMAX 256         // max tiles (T = ceil(E/TILE) = 196); tile id fits uchar

// fp32 -> bf16 round-to-nearest-even.
__device__ inline unsigned f2bf(float f) {
    const unsigned u = __float_as_uint(f);
    return (u + 0x7FFFu + ((u >> 16) & 1u)) >> 16;
}
__device__ inline float bf_lo(unsigned u) { return __uint_as_float(u << 16); }
__device__ inline float bf_hi(unsigned u) { return __uint_as_float(u & 0xFFFF0000u); }

// MFMA fragment types (guide §3: 8 bf16 = 4 VGPRs, 4 fp32 acc).
using bf16x8 = __attribute__((ext_vector_type(8))) short;
using f32x4  = __attribute__((ext_vector_type(4))) float;

// Shared-memory union: gemm role vs multisplit role (whole-block roles).
struct GemmSh {
    unsigned short xt[GROWS * XBSTRIDE];    // 34.8 KB bf16 x tile (k contiguous per row)
    unsigned short wth[F_OUT * XBSTRIDE];   // 17.4 KB w^T hi  (bf16, [col][k])
    unsigned short wtl[F_OUT * XBSTRIDE];   // 17.4 KB w^T lo residual (bf16, [col][k])
};                                          // = 69.6 KB
struct ScatSh {
    int2 ebuf2[TILE];                        // 64 KB (rank-permuted records)
    int  h[BCAP];                            // 3.2 KB
    int  lcur[BCAP];                         // 3.2 KB
    int  wsum[16];
    int  woff[16];
};                                           // = 70.6 KB
union FusedSh { GemmSh g; ScatSh s; };       // ~70.6 KB -> 2 blocks/CU

// ---------------------------------------------------------------------------
// Fused kernel: blocks [0,T) = tile-private edge multisplit; blocks [T,T+G) =
// support = x @ w via MFMA 16x16x32 bf16 (w split hi+lo bf16 ~= fp32 weights).
// toff written TRANSPOSED: toff[bucket*T + tile] (coalesced baccum prologue).
// ---------------------------------------------------------------------------
__global__ __launch_bounds__(BSTH) void fused_kernel(const float* __restrict__ x,
                                                     const float* __restrict__ w,
                                                     unsigned short* __restrict__ support,
                                                     int n_nodes,
                                                     const float* __restrict__ edge_val,
                                                     const int* __restrict__ edge_src,
                                                     const int* __restrict__ edge_dst,
                                                     int* __restrict__ toff,
                                                     int2* __restrict__ sorted,
                                                     int n_edges, int nb, int T) {
    __shared__ FusedSh u;
    const int tid = threadIdx.x;

    if ((int)blockIdx.x >= T) {
        // ================= gemm role (MFMA) =================
        const int row0 = (blockIdx.x - T) * GROWS;

        {   // stage w^T as bf16 hi/lo: thread i -> col = i&63, k = (i>>6)*8 .. +7
            #pragma unroll
            for (int i = tid; i < F_OUT * (F_IN / 8); i += BSTH) {   // 1024 items
                const int col = i & 63;
                const int kb  = (i >> 6) << 3;
                unsigned short sh[8], sl[8];
                #pragma unroll
                for (int j = 0; j < 8; ++j) {
                    const float f = w[(size_t)(kb + j) * F_OUT + col];   // coalesced per j
                    const unsigned h = f2bf(f);
                    sh[j] = (unsigned short)h;
                    sl[j] = (unsigned short)f2bf(f - __uint_as_float(h << 16));
                }
                uint4 oh, ol;
                oh.x = sh[0] | ((unsigned)sh[1] << 16); oh.y = sh[2] | ((unsigned)sh[3] << 16);
                oh.z = sh[4] | ((unsigned)sh[5] << 16); oh.w = sh[6] | ((unsigned)sh[7] << 16);
                ol.x = sl[0] | ((unsigned)sl[1] << 16); ol.y = sl[2] | ((unsigned)sl[3] << 16);
                ol.z = sl[4] | ((unsigned)sl[5] << 16); ol.w = sl[6] | ((unsigned)sl[7] << 16);
                *(uint4*)&u.g.wth[col * XBSTRIDE + kb] = oh;
                *(uint4*)&u.g.wtl[col * XBSTRIDE + kb] = ol;
            }
        }
        {   // stage x tile as bf16: 128 rows x 16 chunks of 8 k's, 2/thread
            const float4* x4 = (const float4*)x;
            #pragma unroll
            for (int i = tid; i < GROWS * (F_IN / 8); i += BSTH) {
                const int r  = i >> 4;       // row 0..127
                const int k8 = i & 15;       // 8-k chunk 0..15
                const int row = row0 + r;
                float4 a = make_float4(0.f, 0.f, 0.f, 0.f);
                float4 b = make_float4(0.f, 0.f, 0.f, 0.f);
                if (row < n_nodes) {
                    a = x4[(size_t)row * (F_IN / 4) + 2 * k8 + 0];
                    b = x4[(size_t)row * (F_IN / 4) + 2 * k8 + 1];
                }
                uint4 o;
                o.x = f2bf(a.x) | (f2bf(a.y) << 16);
                o.y = f2bf(a.z) | (f2bf(a.w) << 16);
                o.z = f2bf(b.x) | (f2bf(b.y) << 16);
                o.w = f2bf(b.z) | (f2bf(b.w) << 16);
                *(uint4*)&u.g.xt[r * XBSTRIDE + k8 * 8] = o;   // 16B aligned
            }
        }
        __syncthreads();

        const int ln = tid & 63;
        const int wv = tid >> 6;             // wave 0..15
        const int rt = wv >> 1;              // row-tile 0..7
        const int cp = (wv & 1) << 1;        // col-tile base: 0 or 2
        const int lr = ln >> 4;              // 0..3 (k-subchunk / out row-quad)
        const int lc = ln & 15;

        const unsigned short* ar  = &u.g.xt [(rt * 16 + lc) * XBSTRIDE + lr * 8];
        const unsigned short* bh0 = &u.g.wth[(cp * 16 + lc) * XBSTRIDE + lr * 8];
        const unsigned short* bh1 = &u.g.wth[((cp + 1) * 16 + lc) * XBSTRIDE + lr * 8];
        const unsigned short* bl0 = &u.g.wtl[(cp * 16 + lc) * XBSTRIDE + lr * 8];
        const unsigned short* bl1 = &u.g.wtl[((cp + 1) * 16 + lc) * XBSTRIDE + lr * 8];

        f32x4 acc0 = {0.f, 0.f, 0.f, 0.f};
        f32x4 acc1 = {0.f, 0.f, 0.f, 0.f};
        #pragma unroll
        for (int kc = 0; kc < 4; ++kc) {
            const bf16x8 a  = *(const bf16x8*)(ar  + kc * 32);
            const bf16x8 h0 = *(const bf16x8*)(bh0 + kc * 32);
            const bf16x8 h1 = *(const bf16x8*)(bh1 + kc * 32);
            const bf16x8 l0 = *(const bf16x8*)(bl0 + kc * 32);
            const bf16x8 l1 = *(const bf16x8*)(bl1 + kc * 32);
            acc0 = __builtin_amdgcn_mfma_f32_16x16x32_bf16(a, h0, acc0, 0, 0, 0);
            acc1 = __builtin_amdgcn_mfma_f32_16x16x32_bf16(a, h1, acc1, 0, 0, 0);
            acc0 = __builtin_amdgcn_mfma_f32_16x16x32_bf16(a, l0, acc0, 0, 0, 0);
            acc1 = __builtin_amdgcn_mfma_f32_16x16x32_bf16(a, l1, acc1, 0, 0, 0);
        }

        #pragma unroll
        for (int i = 0; i < 4; ++i) {
            const int row = row0 + rt * 16 + lr * 4 + i;
            if (row < n_nodes) {
                unsigned short* sp = &support[(size_t)row * F_OUT + lc];
                sp[cp * 16]       = (unsigned short)f2bf(acc0[i]);
                sp[(cp + 1) * 16] = (unsigned short)f2bf(acc1[i]);
            }
        }
        return;
    }

    // ================= multisplit role =================
    const int te  = blockIdx.x * TILE;
    const int cnt = min(TILE, n_edges - te);

    for (int i = tid; i < BCAP; i += BSTH) u.s.h[i] = 0;
    __syncthreads();

    // Pass A: load edges into REGISTERS (2 int4-tiles/thread) + LDS hist.
    const int cnt4 = cnt >> 2;
    const int4*   s4 = (const int4*)(edge_src + te);
    const int4*   d4 = (const int4*)(edge_dst + te);
    const float4* v4 = (const float4*)(edge_val + te);
    int4 rs[2], rd[2]; float4 rv[2];
    #pragma unroll
    for (int it = 0; it < 2; ++it) {
        const int t = tid + it * BSTH;
        if (t < cnt4) {
            rs[it] = s4[t]; rd[it] = d4[t]; rv[it] = v4[t];
            atomicAdd(&u.s.h[rd[it].x >> NPB_SHIFT], 1);
            atomicAdd(&u.s.h[rd[it].y >> NPB_SHIFT], 1);
            atomicAdd(&u.s.h[rd[it].z >> NPB_SHIFT], 1);
            atomicAdd(&u.s.h[rd[it].w >> NPB_SHIFT], 1);
        }
    }
    if (tid == 0) {   // tail (<=3 edges): hist only, ranked in pass B
        for (int e = cnt4 << 2; e < cnt; ++e)
            atomicAdd(&u.s.h[edge_dst[te + e] >> NPB_SHIFT], 1);
    }
    __syncthreads();

    // Shuffle-based block scan of bucket counts (16 waves).
    const int v = (tid < nb) ? u.s.h[tid] : 0;
    int s = v;
    #pragma unroll
    for (int off = 1; off < 64; off <<= 1) {
        const int t = __shfl_up(s, off, 64);
        if ((tid & 63) >= off) s += t;
    }
    const int wave = tid >> 6;
    if ((tid & 63) == 63) u.s.wsum[wave] = s;
    __syncthreads();
    if (tid < 16) {
        const int ws = u.s.wsum[tid];
        int sc = ws;
        #pragma unroll
        for (int off = 1; off < 16; off <<= 1) {
            const int t = __shfl_up(sc, off, 64);
            if (tid >= off) sc += t;
        }
        u.s.woff[tid] = sc - ws;   // exclusive wave offset
    }
    __syncthreads();

    {   // TRANSPOSED toff stores: toff[bucket*T + tile]
        const int bid = blockIdx.x;
        if (tid < nb) {
            const int start = s + u.s.woff[wave] - v;   // exclusive start
            u.s.lcur[tid] = start;
            toff[(size_t)tid * T + bid] = start;
        }
        if (tid == 0) toff[(size_t)nb * T + bid] = cnt;
    }
    __syncthreads();

    // Pass B: rank (LDS cursor) and write records DIRECTLY permuted into LDS.
    #pragma unroll
    for (int it = 0; it < 2; ++it) {
        const int t = tid + it * BSTH;
        if (t < cnt4) {
            int b, r;
            b = rd[it].x >> NPB_SHIFT; r = atomicAdd(&u.s.lcur[b], 1);
            u.s.ebuf2[r] = make_int2(rs[it].x | ((rd[it].x & (NPB - 1)) << 20), __float_as_int(rv[it].x));
            b = rd[it].y >> NPB_SHIFT; r = atomicAdd(&u.s.lcur[b], 1);
            u.s.ebuf2[r] = make_int2(rs[it].y | ((rd[it].y & (NPB - 1)) << 20), __float_as_int(rv[it].y));
            b = rd[it].z >> NPB_SHIFT; r = atomicAdd(&u.s.lcur[b], 1);
            u.s.ebuf2[r] = make_int2(rs[it].z | ((rd[it].z & (NPB - 1)) << 20), __float_as_int(rv[it].z));
            b = rd[it].w >> NPB_SHIFT; r = atomicAdd(&u.s.lcur[b], 1);
            u.s.ebuf2[r] = make_int2(rs[it].w | ((rd[it].w & (NPB - 1)) << 20), __float_as_int(rv[it].w));
        }
    }
    if (tid == 0) {   // tail
        for (int e = cnt4 << 2; e < cnt; ++e) {
            const int dd = edge_dst[te + e];
            const int b = dd >> NPB_SHIFT;
            const int r = atomicAdd(&u.s.lcur[b], 1);
            u.s.ebuf2[r] = make_int2(edge_src[te + e] | ((dd & (NPB - 1)) << 20),
                                     __float_as_int(edge_val[te + e]));
        }
    }
    __syncthreads();

    // Pass C: stream the sorted tile to its private region (coalesced).
    for (int k = tid; k < cnt; k += BSTH)
        sorted[(size_t)te + k] = u.s.ebuf2[k];
}

// ---------------------------------------------------------------------------
// baccum v4 = r5 structure (45.5 us proven) + two local changes:
//  (1) staging keeps the coalesced position-ordered read, but position->tile
//      comes from a 2.2KB LDS tileof[] byte table (1 dep LDS read) instead of
//      an 8-step dependent binary search (~960 cy serial per record).
//  (2) gather uses work-stealing: 8-lane groups claim nodes via LDS INT
//      atomicAdd (+shfl broadcast) and write out per node when done.  Kills
//      the static-assignment straggler (wave iterated max of 8 Poisson sums,
//      ~40% overhead).  Int LDS atomics are fast; only fp32 LDS atomicAdd is
//      CAS-poison (r4).  Plain __launch_bounds__(512): min-waves forces spill
//      (r2).  No staged re-reads (r6: 10/64-lane segment copies regressed).
// Slow path (total > ECAP) = r1/r5-proven chunked binsearch, untouched.
// ---------------------------------------------------------------------------
__global__ __launch_bounds__(512) void baccum_kernel(const unsigned short* __restrict__ support,
                                                     const int2* __restrict__ sorted,
                                                     const int* __restrict__ toff,
                                                     float* __restrict__ out,
                                                     int n_nodes, int T, int nb) {
    __shared__ int2 ebuf[ECAP];
    __shared__ int2 ebuf2[ECAP];
    __shared__ unsigned char tileof[ECAP];
    __shared__ int tstart[TMAX];
    __shared__ int toffb[TMAX];
    __shared__ int tlen_s[TMAX];
    __shared__ int wsum3[4];
    __shared__ int total_s;
    __shared__ int hist[NPB];
    __shared__ int node_off[NPB + 1];
    __shared__ int cursor[NPB];
    __shared__ int wsum2[2];
    __shared__ int next_node;

    const int tid = threadIdx.x;
    const int b = blockIdx.x;

    int mycnt = 0, myoff = 0;
    if (tid < TMAX) {
        if (tid < T) {
            const int s0 = toff[(size_t)b * T + tid];          // coalesced row b
            const int e0 = toff[(size_t)(b + 1) * T + tid];    // coalesced row b+1
            toffb[tid] = s0;
            mycnt = e0 - s0;
            tlen_s[tid] = mycnt;
        }
        int s = mycnt;
        #pragma unroll
        for (int off = 1; off < 64; off <<= 1) {
            const int t = __shfl_up(s, off, 64);
            if ((tid & 63) >= off) s += t;
        }
        if ((tid & 63) == 63) wsum3[tid >> 6] = s;
        myoff = s - mycnt;
    }
    __syncthreads();
    if (tid < TMAX && tid < T) {
        int add = 0;
        const int wv = tid >> 6;
        for (int q2 = 0; q2 < wv; ++q2) add += wsum3[q2];
        tstart[tid] = myoff + add;
    }
    if (tid == 0) { total_s = wsum3[0] + wsum3[1] + wsum3[2] + wsum3[3]; next_node = 0; }
    __syncthreads();
    const int total = total_s;

    const int g8 = tid >> 3;        // group 0..63
    const int q  = tid & 7;         // uint4 slot: feats 8q..8q+7
    const int ln = tid & 63;
    const uint4* sup = (const uint4*)support;   // row = 8 uint4 = 128 B

    // Shared scan body: hist -> node_off (+1-incl), cursor (excl).
    auto scan_bins = [&]() {
        int v = 0;
        if (tid < NPB) v = hist[tid];
        int s = v;
        if (tid < NPB) {
            #pragma unroll
            for (int off = 1; off < 64; off <<= 1) {
                const int t = __shfl_up(s, off, 64);
                if ((tid & 63) >= off) s += t;
            }
            if ((tid & 63) == 63) wsum2[tid >> 6] = s;
        }
        __syncthreads();
        if (tid < NPB) {
            const int incl = s + ((tid >= 64) ? wsum2[0] : 0);
            node_off[tid + 1] = incl;
            cursor[tid] = incl - v;
            if (tid == 0) node_off[0] = 0;
        }
    };

    if (total <= ECAP) {
        // ==================== fast path ====================
        if (tid < NPB) hist[tid] = 0;
        // tileof fill: thread t writes its segment's ~10 bytes (tstart visible
        // after the barrier above).
        for (int t = tid; t < T; t += 512) {
            const int s0 = tstart[t];
            const int len = tlen_s[t];
            for (int j2 = 0; j2 < len; ++j2) tileof[s0 + j2] = (unsigned char)t;
        }
        __syncthreads();

        // Stage + hist: coalesced position-ordered read, table lookup for tile.
        for (int i = tid; i < total; i += 512) {
            const int t = (int)tileof[i];
            const int2 ev = sorted[(size_t)t * TILE + toffb[t] + (i - tstart[t])];
            ebuf[i] = ev;
            atomicAdd(&hist[((unsigned)ev.x) >> 20], 1);
        }
        __syncthreads();

        scan_bins();
        __syncthreads();

        // Permute into dstLocal-grouped ebuf2 (LDS only).
        for (int i = tid; i < total; i += 512) {
            const int2 ev = ebuf[i];
            const int r = atomicAdd(&cursor[((unsigned)ev.x) >> 20], 1);
            ebuf2[r] = ev;
        }
        __syncthreads();

        // Work-stealing gather: groups claim nodes dynamically; write per node.
        while (true) {
            int n = 0;
            if (q == 0) n = atomicAdd(&next_node, 1);
            n = __shfl(n, ln & ~7, 64);
            if (n >= NPB) break;

            int k = node_off[n];
            const int ke = node_off[n + 1];
            float4 aA = make_float4(0.f, 0.f, 0.f, 0.f);
            float4 aB = make_float4(0.f, 0.f, 0.f, 0.f);
            while (k + 8 <= ke) {
                int2 e[8];
                uint4 s8[8];
                #pragma unroll
                for (int u2 = 0; u2 < 8; ++u2) e[u2] = ebuf2[k + u2];      // broadcast
                #pragma unroll
                for (int u2 = 0; u2 < 8; ++u2)
                    s8[u2] = sup[(size_t)(e[u2].x & 0xFFFFF) * 8 + q];     // independent
                #pragma unroll
                for (int u2 = 0; u2 < 8; ++u2) {
                    const float v = __int_as_float(e[u2].y);
                    aA.x += v * bf_lo(s8[u2].x); aA.y += v * bf_hi(s8[u2].x);
                    aA.z += v * bf_lo(s8[u2].y); aA.w += v * bf_hi(s8[u2].y);
                    aB.x += v * bf_lo(s8[u2].z); aB.y += v * bf_hi(s8[u2].z);
                    aB.z += v * bf_lo(s8[u2].w); aB.w += v * bf_hi(s8[u2].w);
                }
                k += 8;
            }
            for (; k < ke; ++k) {
                const int2 e0 = ebuf2[k];
                const uint4 s0 = sup[(size_t)(e0.x & 0xFFFFF) * 8 + q];
                const float v0 = __int_as_float(e0.y);
                aA.x += v0 * bf_lo(s0.x); aA.y += v0 * bf_hi(s0.x);
                aA.z += v0 * bf_lo(s0.y); aA.w += v0 * bf_hi(s0.y);
                aB.x += v0 * bf_lo(s0.z); aB.y += v0 * bf_hi(s0.z);
                aB.z += v0 * bf_lo(s0.w); aB.w += v0 * bf_hi(s0.w);
            }

            const int node = (b << NPB_SHIFT) + n;
            if (node < n_nodes) {
                aA.x = fmaxf(aA.x, 0.f); aA.y = fmaxf(aA.y, 0.f);
                aA.z = fmaxf(aA.z, 0.f); aA.w = fmaxf(aA.w, 0.f);
                aB.x = fmaxf(aB.x, 0.f); aB.y = fmaxf(aB.y, 0.f);
                aB.z = fmaxf(aB.z, 0.f); aB.w = fmaxf(aB.w, 0.f);
                ((float4*)out)[(size_t)node * 16 + 2 * q + 0] = aA;
                ((float4*)out)[(size_t)node * 16 + 2 * q + 1] = aB;
            }
        }
        return;
    }

    // ==================== slow path (r1/r5-proven, any distribution) ====================
    float4 accA[2], accB[2];
    #pragma unroll
    for (int j = 0; j < 2; ++j) {
        accA[j] = make_float4(0.f, 0.f, 0.f, 0.f);
        accB[j] = make_float4(0.f, 0.f, 0.f, 0.f);
    }

    for (int cb = 0; cb < total; cb += ECAP) {
        const int cnt = min(ECAP, total - cb);

        __syncthreads();
        if (tid < NPB) hist[tid] = 0;
        __syncthreads();

        for (int i = tid; i < cnt; i += 512) {
            const int g = cb + i;
            int lo = 0, hi = T - 1;
            while (lo < hi) {
                const int mid = (lo + hi + 1) >> 1;
                if (tstart[mid] <= g) lo = mid; else hi = mid - 1;
            }
            const int2 ev = sorted[(size_t)lo * TILE + toffb[lo] + (g - tstart[lo])];
            ebuf[i] = ev;
            atomicAdd(&hist[((unsigned)ev.x) >> 20], 1);
        }
        __syncthreads();

        scan_bins();
        __syncthreads();

        for (int i = tid; i < cnt; i += 512) {
            const int2 ev = ebuf[i];
            const int r = atomicAdd(&cursor[((unsigned)ev.x) >> 20], 1);
            ebuf2[r] = ev;
        }
        __syncthreads();

        #pragma unroll
        for (int j = 0; j < 2; ++j) {
            const int nl = g8 + 64 * j;
            int k = node_off[nl];
            const int ke = node_off[nl + 1];
            float4 aA = accA[j], aB = accB[j];
            while (k + 8 <= ke) {
                int2 e[8];
                uint4 s8[8];
                #pragma unroll
                for (int u2 = 0; u2 < 8; ++u2) e[u2] = ebuf2[k + u2];
                #pragma unroll
                for (int u2 = 0; u2 < 8; ++u2)
                    s8[u2] = sup[(size_t)(e[u2].x & 0xFFFFF) * 8 + q];
                #pragma unroll
                for (int u2 = 0; u2 < 8; ++u2) {
                    const float v = __int_as_float(e[u2].y);
                    aA.x += v * bf_lo(s8[u2].x); aA.y += v * bf_hi(s8[u2].x);
                    aA.z += v * bf_lo(s8[u2].y); aA.w += v * bf_hi(s8[u2].y);
                    aB.x += v * bf_lo(s8[u2].z); aB.y += v * bf_hi(s8[u2].z);
                    aB.z += v * bf_lo(s8[u2].w); aB.w += v * bf_hi(s8[u2].w);
                }
                k += 8;
            }
            for (; k < ke; ++k) {
                const int2 e0 = ebuf2[k];
                const uint4 s0 = sup[(size_t)(e0.x & 0xFFFFF) * 8 + q];
                const float v0 = __int_as_float(e0.y);
                aA.x += v0 * bf_lo(s0.x); aA.y += v0 * bf_hi(s0.x);
                aA.z += v0 * bf_lo(s0.y); aA.w += v0 * bf_hi(s0.y);
                aB.x += v0 * bf_lo(s0.z); aB.y += v0 * bf_hi(s0.z);
                aB.z += v0 * bf_lo(s0.w); aB.w += v0 * bf_hi(s0.w);
            }
            accA[j] = aA; accB[j] = aB;
        }
    }

    const int base = b << NPB_SHIFT;
    #pragma unroll
    for (int j = 0; j < 2; ++j) {
        const int node = base + g8 + 64 * j;
        if (node < n_nodes) {
            float4 vA = accA[j], vB = accB[j];
            vA.x = fmaxf(vA.x, 0.f); vA.y = fmaxf(vA.y, 0.f);
            vA.z = fmaxf(vA.z, 0.f); vA.w = fmaxf(vA.w, 0.f);
            vB.x = fmaxf(vB.x, 0.f); vB.y = fmaxf(vB.y, 0.f);
            vB.z = fmaxf(vB.z, 0.f); vB.w = fmaxf(vB.w, 0.f);
            ((float4*)out)[(size_t)node * 16 + 2 * q + 0] = vA;
            ((float4*)out)[(size_t)node * 16 + 2 * q + 1] = vB;
        }
    }
}

// ---------------------------------------------------------------------------
// Fallback: atomic path with bf16 support.
// ---------------------------------------------------------------------------
__global__ __launch_bounds__(256) void scatter_kernel(const unsigned short* __restrict__ support,
                                                      const float* __restrict__ edge_val,
                                                      const int* __restrict__ edge_src,
                                                      const int* __restrict__ edge_dst,
                                                      float* __restrict__ out,
                                                      int n_edges) {
    const long gid = (long)blockIdx.x * blockDim.x + threadIdx.x;
    const int e = (int)(gid >> 4);
    if (e >= n_edges) return;
    const int q = (int)(gid & 15);
    const int src   = edge_src[e];
    const int dst   = edge_dst[e];
    const float val = edge_val[e];
    const uint2 s = ((const uint2*)support)[(size_t)src * 16 + q];
    float* o = &out[(size_t)dst * F_OUT + q * 4];
    atomicAdd(o + 0, val * bf_lo(s.x));
    atomicAdd(o + 1, val * bf_hi(s.x));
    atomicAdd(o + 2, val * bf_lo(s.y));
    atomicAdd(o + 3, val * bf_hi(s.y));
}

__global__ __launch_bounds__(256) void relu_kernel(float* __restrict__ out, int n4) {
    const int i = blockIdx.x * blockDim.x + threadIdx.x;
    if (i < n4) {
        float4 v = ((float4*)out)[i];
        v.x = fmaxf(v.x, 0.f); v.y = fmaxf(v.y, 0.f);
        v.z = fmaxf(v.z, 0.f); v.w = fmaxf(v.w, 0.f);
        ((float4*)out)[i] = v;
    }
}

extern "C" void kernel_launch(void* const* d_in, const int* in_sizes, int n_in,
                              void* d_out, int out_size, void* d_ws, size_t ws_size,
                              hipStream_t stream) {
    const float* x        = (const float*)d_in[0];
    const float* w        = (const float*)d_in[1];
    const float* edge_val = (const float*)d_in[2];
    const int*   edge_src = (const int*)d_in[3];
    const int*   edge_dst = (const int*)d_in[4];
    float* out = (float*)d_out;

    const int n_nodes = in_sizes[0] / F_IN;   // 100000
    const int n_edges = in_sizes[2];          // 1600000
    const int nb = (n_nodes + NPB - 1) >> NPB_SHIFT;   // 782 buckets
    const int T  = (n_edges + TILE - 1) / TILE;        // 196 tiles
    const int G  = (n_nodes + GROWS - 1) / GROWS;      // 782 gemm blocks

    // Workspace: support bf16 (12.8 MB) | sorted (12.85 MB) | toff (0.61 MB)
    char* p = (char*)d_ws;
    unsigned short* support = (unsigned short*)p;
    p += (size_t)n_nodes * F_OUT * sizeof(unsigned short);
    p = (char*)(((size_t)p + 15) & ~(size_t)15);
    int2* sorted = (int2*)p;  p += (size_t)T * TILE * sizeof(int2);
    int*  toff   = (int*)p;   p += (size_t)(nb + 1) * T * sizeof(int);
    const size_t ws_needed = (size_t)(p - (char*)d_ws);

    const bool ok = (ws_size >= ws_needed) && (nb <= BCAP) && (n_nodes < (1 << 20))
                    && (T <= TMAX);
    if (ok) {
        fused_kernel<<<T + G, BSTH, 0, stream>>>(x, w, support, n_nodes,
                                                 edge_val, edge_src, edge_dst,
                                                 toff, sorted, n_edges, nb, T);
        baccum_kernel<<<nb, 512, 0, stream>>>(support, sorted, toff, out,
                                              n_nodes, T, nb);
    } else {
        // gemm only (T=0 -> all blocks take the gemm role)
        fused_kernel<<<G, BSTH, 0, stream>>>(x, w, support, n_nodes,
                                             edge_val, edge_src, edge_dst,
                                             nullptr, nullptr, n_edges, nb, 0);
        hipMemsetAsync(d_out, 0, (size_t)out_size * sizeof(float), stream);
        const long st = (long)n_edges * 16;
        scatter_kernel<<<(int)((st + 255) / 256), 256, 0, stream>>>(
            support, edge_val, edge_src, edge_dst, out, n_edges);
        const int n4o = out_size / 4;
        relu_kernel<<<(n4o + 255) / 256, 256, 0, stream>>>(out, n4o);
    }
}